// Round 4
// baseline (475.331 us; speedup 1.0000x reference)
//
#include <hip/hip_runtime.h>

#define TT 1024
#define NB 4096
#define HH 50
#define DTC 0.1f
#define NL2E2 -2.8853900817779268f   // -2*log2(e); state is h' = NL2E2*h
#define INVS  (-0.34657359027997264f) // 1/NL2E2

typedef __attribute__((ext_vector_type(8))) short short8;
typedef __attribute__((ext_vector_type(4))) float float4v;
typedef __attribute__((ext_vector_type(4))) unsigned int uint4v;

__device__ __forceinline__ unsigned short f2bf(float f) {
    unsigned int u = __builtin_bit_cast(unsigned int, f);
    u += 0x7FFFu + ((u >> 16) & 1u);   // RNE
    return (unsigned short)(u >> 16);
}

// Logical augmented matrix (all scaled by NL2E2; sigmoid-1/2 and dt folded):
//   rows 0..49:  [0.2*Jrec | 0.1*bias | 0.1*Jin | 0]
//   row  50:     [0.2*Jout@Jrec | 0.1*Jout@bias | 0.1*Jout@Jin | 0]  (out recurrence)
//   rows 51..63: 0.   B slots: 0..49 = rcp(1+exp2(h')), 50 = 1, 51 = x_t.
// Stored GATHERED per M-tile t with row map rho_t(d)=32(t>>1)+4(t&1)+8(d>>2)+(d&3):
// the 16 C-rows lane (q,n) produces are exactly its 16 B k-slots next step.
__global__ void setup_kernel(const float* __restrict__ Jin,
                             const float* __restrict__ Jrec,
                             const float* __restrict__ Jout,
                             const float* __restrict__ bias,
                             const float* __restrict__ h0,
                             float* __restrict__ out0,
                             unsigned short* __restrict__ Astore) {
    const int tid = threadIdx.x;
    const int blk = blockIdx.x;
    if (blk < 16) {
        const int col = blk * 256 + tid;
        float s = 0.f;
        for (int i = 0; i < HH; ++i) s += Jout[i] * h0[i * NB + col];
        out0[col] = s;
    } else {
        // Astore[((t*2+c)*64 + lane)*8 + j] = NL2E2 * A_logical[rho_t(m)][32c+8q+j]
        for (int idx = tid; idx < 4096; idx += 256) {
            const int j = idx & 7;
            const int lane = (idx >> 3) & 63;
            const int tc = idx >> 9;            // 0..7
            const int t = tc >> 1, c = tc & 1;
            const int q = lane >> 4, m = lane & 15;
            const int srow = 32 * (t >> 1) + 4 * (t & 1) + 8 * (m >> 2) + (m & 3);
            const int scol = 32 * c + 8 * q + j;
            float v = 0.f;
            if (srow < HH) {
                if (scol < HH)           v = 2.0f * DTC * Jrec[srow * HH + scol];
                else if (scol == HH)     v = DTC * bias[srow];
                else if (scol == HH + 1) v = DTC * Jin[srow];
            } else if (srow == HH) {
                if (scol < HH) {
                    float s = 0.f;
                    for (int i = 0; i < HH; ++i) s += Jout[i] * Jrec[i * HH + scol];
                    v = 2.0f * DTC * s;
                } else if (scol == HH) {
                    float s = 0.f;
                    for (int i = 0; i < HH; ++i) s += Jout[i] * bias[i];
                    v = DTC * s;
                } else if (scol == HH + 1) {
                    float s = 0.f;
                    for (int i = 0; i < HH; ++i) s += Jout[i] * Jin[i];
                    v = DTC * s;
                }
            }
            Astore[idx] = f2bf(NL2E2 * v);
        }
    }
}

// 256 blocks x 64 threads: one wave owns 16 columns and the FULL 64-row state.
// No LDS, no barriers: B-frags rebuilt from accumulators in-registers each step.
__global__ void __launch_bounds__(64) rnn_kernel(
        const float* __restrict__ x,
        const float* __restrict__ h0,
        const float* __restrict__ out0,
        const unsigned short* __restrict__ Astore,
        float* __restrict__ out) {
    const int lane = threadIdx.x;
    const int q = lane >> 4, n = lane & 15;
    const int col = (blockIdx.x << 4) + n;
    const bool sp = (q == 2);                 // lanes owning k-slots 48..51 (out=50, x=51)

    // A fragments: 4 tiles x 2 k-chunks, 16B per lane each
    short8 Af[4][2];
    const short8* Ap = (const short8*)Astore;
#pragma unroll
    for (int t = 0; t < 4; ++t)
#pragma unroll
        for (int c = 0; c < 2; ++c)
            Af[t][c] = Ap[(t * 2 + c) * 64 + lane];

    // h state (scaled): h[t][r] holds state row 32(t>>1)+4(t&1)+8q+r, column col
    float h[4][4];
    const float vo = out0[col];
#pragma unroll
    for (int t = 0; t < 4; ++t)
#pragma unroll
        for (int r = 0; r < 4; ++r) {
            const int row = 32 * (t >> 1) + 4 * (t & 1) + 8 * q + r;
            const int rc = (row < HH) ? row : 0;
            float v = h0[rc * NB + col];
            v = (row < HH) ? v : ((row == HH) ? vo : 0.f);
            h[t][r] = NL2E2 * v;
        }

    const float* xp = x + col;
    float* outp = out + col;
    float xw = 0.f, xn1 = 0.f, xn2 = 0.f;
    if (sp) { xw = xp[0]; xn1 = xp[NB]; xn2 = xp[2 * NB]; }

    unsigned int bu[4][2];
    // pack r' = rcp(1+exp2(h')) for tile t into 2 dwords (bf16, round-half-up)
#define PACKT(t, xv)                                                          \
    {                                                                         \
        unsigned int u[4];                                                    \
        _Pragma("unroll")                                                     \
        for (int r = 0; r < 4; ++r) {                                         \
            float e = __builtin_amdgcn_exp2f(h[t][r]);                        \
            float rv = __builtin_amdgcn_rcpf(1.0f + e);                       \
            u[r] = __builtin_bit_cast(unsigned int, rv);                      \
        }                                                                     \
        if ((t) == 2) {                                                       \
            u[2] = sp ? 0x3F800000u : u[2];                                   \
            u[3] = sp ? __builtin_bit_cast(unsigned int, (xv)) : u[3];        \
        }                                                                     \
        _Pragma("unroll")                                                     \
        for (int r = 0; r < 4; ++r) u[r] += 0x8000u;                          \
        bu[t][0] = __builtin_amdgcn_perm(u[1], u[0], 0x07060302u);            \
        bu[t][1] = __builtin_amdgcn_perm(u[3], u[2], 0x07060302u);            \
    }

    PACKT(0, 0.f) PACKT(1, 0.f) PACKT(2, xw) PACKT(3, 0.f)

#pragma unroll 2
    for (int t = 0; t < TT; ++t) {
        uint4v b0u = {bu[0][0], bu[0][1], bu[1][0], bu[1][1]};
        uint4v b1u = {bu[2][0], bu[2][1], bu[3][0], bu[3][1]};
        short8 b0 = __builtin_bit_cast(short8, b0u);
        short8 b1 = __builtin_bit_cast(short8, b1u);

        float xf = 0.f;
        if (sp) {
            const int tt = (t + 3 < TT) ? t + 3 : TT - 1;
            xf = xp[tt * NB];
        }

#pragma unroll
        for (int tt2 = 0; tt2 < 4; ++tt2) {
            float4v c;
#pragma unroll
            for (int r = 0; r < 4; ++r) c[r] = (1.0f - DTC) * h[tt2][r];
            c = __builtin_amdgcn_mfma_f32_16x16x32_bf16(Af[tt2][0], b0, c, 0, 0, 0);
            c = __builtin_amdgcn_mfma_f32_16x16x32_bf16(Af[tt2][1], b1, c, 0, 0, 0);
#pragma unroll
            for (int r = 0; r < 4; ++r) h[tt2][r] = c[r];
        }

        if (sp) outp[t * NB] = h[2][2] * INVS;   // state row 50 = scaled out_t

        PACKT(0, 0.f) PACKT(1, 0.f) PACKT(2, xn1) PACKT(3, 0.f)

        xn1 = xn2; xn2 = xf;
    }
#undef PACKT
}

extern "C" void kernel_launch(void* const* d_in, const int* in_sizes, int n_in,
                              void* d_out, int out_size, void* d_ws, size_t ws_size,
                              hipStream_t stream) {
    (void)in_sizes; (void)n_in; (void)out_size; (void)ws_size;
    const float* x    = (const float*)d_in[0];
    const float* Jin  = (const float*)d_in[1];
    const float* Jrec = (const float*)d_in[2];
    const float* Jout = (const float*)d_in[3];
    const float* bias = (const float*)d_in[4];
    const float* h0   = (const float*)d_in[5];
    float* out = (float*)d_out;

    float* ws_out0 = (float*)d_ws;                            // 4096 f32
    unsigned short* ws_A = (unsigned short*)(ws_out0 + NB);   // 4096 bf16 gathered

    hipLaunchKernelGGL(setup_kernel, dim3(17), dim3(256), 0, stream,
                       Jin, Jrec, Jout, bias, h0, ws_out0, ws_A);
    hipLaunchKernelGGL(rnn_kernel, dim3(256), dim3(64), 0, stream,
                       x, h0, ws_out0, ws_A, out);
}

// Round 5
// 318.673 us; speedup vs baseline: 1.4916x; 1.4916x over previous
//
#include <hip/hip_runtime.h>

#define TT 1024
#define NB 4096
#define HH 50
#define DTC 0.1f
#define NL2E2 -2.8853900817779268f   // -2*log2(e)
#define RSTRIDE 68                   // ushorts/col: 34 dwords -> conflict-free b64 reads

typedef __attribute__((ext_vector_type(8))) short short8;
typedef __attribute__((ext_vector_type(4))) short short4v;
typedef __attribute__((ext_vector_type(4))) float float4v;
typedef __attribute__((ext_vector_type(2))) unsigned int uint2v;

__device__ __forceinline__ unsigned short f2bf(float f) {
    unsigned int u = __builtin_bit_cast(unsigned int, f);
    u += 0x7FFFu + ((u >> 16) & 1u);   // RNE
    return (unsigned short)(u >> 16);
}

// LDS-only barrier: leave global loads/stores in flight (no vmcnt drain).
#define BAR() __asm__ volatile("s_waitcnt lgkmcnt(0)\n\ts_barrier" ::: "memory")

// A_aug 64x64 bf16: rows 0..49 cols 0..49 = 0.2*Jrec; row 50 cols 0..49 = 0.2*Jout@Jrec;
// everything else 0.  Per-row vectors (fp32): jinv = 0.1*Jin (row50: 0.1*Jout@Jin),
// biasv = 0.1*bias (row50: 0.1*Jout@bias).  Update:
//   h_next = A_aug @ sigmoid(2h) + [0.9*h + jinv*x_t + biasv]   (C operand)
// Row 50 then carries out_t exactly.
__global__ void setup_kernel(const float* __restrict__ Jin,
                             const float* __restrict__ Jrec,
                             const float* __restrict__ Jout,
                             const float* __restrict__ bias,
                             const float* __restrict__ h0,
                             float* __restrict__ out0,
                             float* __restrict__ jinv,
                             float* __restrict__ biasv,
                             unsigned short* __restrict__ Aaug) {
    const int tid = threadIdx.x;
    const int blk = blockIdx.x;
    if (blk < 16) {
        const int col = blk * 256 + tid;
        float s = 0.f;
        for (int i = 0; i < HH; ++i) s += Jout[i] * h0[i * NB + col];
        out0[col] = s;
    } else {
        for (int idx = tid; idx < 64 * 64; idx += 256) {
            const int row = idx >> 6, k = idx & 63;
            float v = 0.f;
            if (row < HH && k < HH) v = 2.0f * DTC * Jrec[row * HH + k];
            else if (row == HH && k < HH) {
                float s = 0.f;
                for (int i = 0; i < HH; ++i) s += Jout[i] * Jrec[i * HH + k];
                v = 2.0f * DTC * s;
            }
            Aaug[idx] = f2bf(v);
        }
        if (tid < 64) {
            float ji = 0.f, bi = 0.f;
            if (tid < HH) { ji = DTC * Jin[tid]; bi = DTC * bias[tid]; }
            else if (tid == HH) {
                float sj = 0.f, sb = 0.f;
                for (int i = 0; i < HH; ++i) { sj += Jout[i] * Jin[i]; sb += Jout[i] * bias[i]; }
                ji = DTC * sj; bi = DTC * sb;
            }
            jinv[tid] = ji; biasv[tid] = bi;
        }
    }
}

// 256 blocks x 256 threads; wave w = rows 16w..16w+15, block = 16 batch cols.
// h in fp32 C-layout regs (row = 16w+4q+reg, col = lane&15). Row 50 carries out_t.
// Global I/O batched per 8 steps; inner loop: LDS + MFMA + VALU only.
__global__ void __launch_bounds__(256) rnn_kernel(
        const float* __restrict__ x,
        const float* __restrict__ h0,
        const float* __restrict__ out0,
        const float* __restrict__ jinv,
        const float* __restrict__ biasv,
        const unsigned short* __restrict__ Aaug,
        float* __restrict__ out) {
    __shared__ unsigned short rbuf[2][16][RSTRIDE];

    const int tid  = threadIdx.x;
    const int w    = tid >> 6;
    const int lane = tid & 63;
    const int n    = lane & 15;
    const int q    = lane >> 4;
    const int col  = (blockIdx.x << 4) + n;
    const int row0 = 16 * w + 4 * q;

    // A fragments, contiguous our-k (slot permutation cancels between A and B frags)
    short8 a0, a1;
    {
        const unsigned short* ap = Aaug + ((16 * w + n) << 6) + (q << 3);
        a0 = *(const short8*)ap;
        a1 = *(const short8*)(ap + 32);
    }

    float ji[4], bi[4], h[4];
#pragma unroll
    for (int r = 0; r < 4; ++r) {
        ji[r] = jinv[row0 + r];
        bi[r] = biasv[row0 + r];
        h[r] = (row0 + r < HH) ? h0[(row0 + r) * NB + col] : 0.f;
    }
    const bool outlane = (w == 3) && (q == 0);   // holds row 50 in h[2]
    if (outlane) h[2] = out0[col];

    const float* xp = x + col;
    float* outp = out + col;

    // initial r'(h0) into buffer 0 (uniform: no special slots anymore)
    {
        unsigned int u[4];
#pragma unroll
        for (int r = 0; r < 4; ++r) {
            float e = __builtin_amdgcn_exp2f(NL2E2 * h[r]);
            float rv = __builtin_amdgcn_rcpf(1.0f + e);
            u[r] = __builtin_bit_cast(unsigned int, rv) + 0x8000u;
        }
        uint2v pk;
        pk[0] = __builtin_amdgcn_perm(u[1], u[0], 0x07060302u);
        pk[1] = __builtin_amdgcn_perm(u[3], u[2], 0x07060302u);
        *(uint2v*)&rbuf[0][n][row0] = pk;
    }

    unsigned short* const wr0 = &rbuf[0][n][row0];
    unsigned short* const wr1 = &rbuf[1][n][row0];
    const unsigned short* const rd0 = &rbuf[0][n][q << 3];
    const unsigned short* const rd1 = &rbuf[1][n][q << 3];

    // x batch for group 0
    float xs[8], xt[8], ob[8];
#pragma unroll
    for (int i = 0; i < 8; ++i) xs[i] = xp[i * NB];

    __syncthreads();   // one-time full sync

    for (int g = 0; g < TT / 8; ++g) {
        // prefetch next group's x (waited next group -> off the chain)
        const int base = (g + 1) * 8;
#pragma unroll
        for (int i = 0; i < 8; ++i) {
            const int idx = (base + i < TT) ? base + i : TT - 1;
            xt[i] = xp[idx * NB];
        }

#pragma unroll
        for (int i = 0; i < 8; ++i) {
            // B-frags for this step (written by all waves pre-barrier)
            const unsigned short* rp = (i & 1) ? rd1 : rd0;
            short4v b0a = *(const short4v*)(rp);
            short4v b0b = *(const short4v*)(rp + 4);
            short4v b1a = *(const short4v*)(rp + 32);
            short4v b1b = *(const short4v*)(rp + 36);
            short8 b0 = __builtin_shufflevector(b0a, b0b, 0, 1, 2, 3, 4, 5, 6, 7);
            short8 b1 = __builtin_shufflevector(b1a, b1b, 0, 1, 2, 3, 4, 5, 6, 7);

            // C operand: 0.9*h + jin*x_t + bias  (independent of the LDS read)
            float4v c;
#pragma unroll
            for (int r = 0; r < 4; ++r)
                c[r] = __builtin_fmaf(h[r], 1.0f - DTC,
                                      __builtin_fmaf(ji[r], xs[i], bi[r]));

            c = __builtin_amdgcn_mfma_f32_16x16x32_bf16(a0, b0, c, 0, 0, 0);
            c = __builtin_amdgcn_mfma_f32_16x16x32_bf16(a1, b1, c, 0, 0, 0);
#pragma unroll
            for (int r = 0; r < 4; ++r) h[r] = c[r];

            ob[i] = h[2];   // row 50 = out_t (meaningful in outlanes only)

            // r' = sigmoid(2h) -> bf16 pack -> exchange
            unsigned int u[4];
#pragma unroll
            for (int r = 0; r < 4; ++r) {
                float e = __builtin_amdgcn_exp2f(NL2E2 * h[r]);
                float rv = __builtin_amdgcn_rcpf(1.0f + e);
                u[r] = __builtin_bit_cast(unsigned int, rv) + 0x8000u;
            }
            uint2v pk;
            pk[0] = __builtin_amdgcn_perm(u[1], u[0], 0x07060302u);
            pk[1] = __builtin_amdgcn_perm(u[3], u[2], 0x07060302u);
            *(uint2v*)((i & 1) ? wr0 : wr1) = pk;

            BAR();
        }

        // batched out stores (fire-and-forget) + x rotate
        if (outlane) {
            const int tb = g * 8;
#pragma unroll
            for (int i = 0; i < 8; ++i) outp[(tb + i) * NB] = ob[i];
        }
#pragma unroll
        for (int i = 0; i < 8; ++i) xs[i] = xt[i];
    }
}

extern "C" void kernel_launch(void* const* d_in, const int* in_sizes, int n_in,
                              void* d_out, int out_size, void* d_ws, size_t ws_size,
                              hipStream_t stream) {
    (void)in_sizes; (void)n_in; (void)out_size; (void)ws_size;
    const float* x    = (const float*)d_in[0];
    const float* Jin  = (const float*)d_in[1];
    const float* Jrec = (const float*)d_in[2];
    const float* Jout = (const float*)d_in[3];
    const float* bias = (const float*)d_in[4];
    const float* h0   = (const float*)d_in[5];
    float* out = (float*)d_out;

    float* ws_out0 = (float*)d_ws;                            // 4096 f32
    float* ws_jin  = ws_out0 + NB;                            // 64 f32
    float* ws_bias = ws_jin + 64;                             // 64 f32
    unsigned short* ws_A = (unsigned short*)(ws_bias + 64);   // 4096 bf16

    hipLaunchKernelGGL(setup_kernel, dim3(17), dim3(256), 0, stream,
                       Jin, Jrec, Jout, bias, h0, ws_out0, ws_jin, ws_bias, ws_A);
    hipLaunchKernelGGL(rnn_kernel, dim3(256), dim3(256), 0, stream,
                       x, h0, ws_out0, ws_jin, ws_bias, ws_A, out);
}